// Round 1
// baseline (4083.764 us; speedup 1.0000x reference)
//
#include <hip/hip_runtime.h>
#include <hip/hip_bf16.h>
#include <math.h>

// Problem constants (Glm4MoE)
#define TOKENS  2048
#define HID     2048
#define INT_DIM 1408
#define NEXP    32
#define TOPK    8
#define BK      32
#define LDSP    40   // padded LDS row stride in shorts (32 + 8) -> 80B rows, 16B aligned

typedef __attribute__((ext_vector_type(8))) short bf16x8;
typedef __attribute__((ext_vector_type(4))) float f32x4;

union BV8 { bf16x8 v; unsigned int u[4]; };

__device__ inline unsigned short f2bf(float f) {
    union { float f; unsigned int u; } v; v.f = f;
    unsigned int r = v.u + 0x7fffu + ((v.u >> 16) & 1u);
    return (unsigned short)(r >> 16);
}

__device__ inline unsigned int pk2bf(float a, float b) {
    __hip_bfloat162 h = __float22bfloat162_rn(float2{a, b});
    unsigned int r;
    __builtin_memcpy(&r, &h, 4);
    return r;
}

// ---------------- gate: fp64 logits, sigmoid, top-8, bucket append ----------------
__global__ __launch_bounds__(256) void gate_kernel(
    const float* __restrict__ X, const float* __restrict__ GW,
    const float* __restrict__ GB, int* __restrict__ cnt,
    int* __restrict__ tok_list, float* __restrict__ wt_list)
{
    int t = blockIdx.x;
    int tid = threadIdx.x;
    int e = tid >> 3, j = tid & 7;
    const float* x = X + (size_t)t * HID;
    const float* g = GW + (size_t)e * HID;
    double s = 0.0;
    for (int k = j; k < HID; k += 8)
        s += (double)x[k] * (double)g[k];
    __shared__ double part[256];
    __shared__ double score[NEXP];
    __shared__ double sel[NEXP];
    part[tid] = s;
    __syncthreads();
    if (tid < NEXP) {
        double acc = 0.0;
        #pragma unroll
        for (int q = 0; q < 8; ++q) acc += part[tid * 8 + q];
        double sc = 1.0 / (1.0 + exp(-acc));
        score[tid] = sc;
        sel[tid] = sc + (double)GB[tid];
    }
    __syncthreads();
    if (tid == 0) {
        int idxs[TOPK];
        double wsum = 0.0;
        for (int it = 0; it < TOPK; ++it) {
            double best = -1e300; int bi = 0;
            for (int ee = 0; ee < NEXP; ++ee) {
                if (sel[ee] > best) { best = sel[ee]; bi = ee; }  // ties -> lowest index (jax top_k)
            }
            sel[bi] = -1e300;
            idxs[it] = bi;
            wsum += score[bi];
        }
        for (int it = 0; it < TOPK; ++it) {
            int ee = idxs[it];
            float w = (float)(score[ee] / wsum);   // ROUTED_SCALING = 1.0
            int slot = atomicAdd(&cnt[ee], 1);
            tok_list[ee * TOKENS + slot] = t;
            wt_list[ee * TOKENS + slot] = w;
        }
    }
}

__global__ void prefix_kernel(const int* __restrict__ cnt, int* __restrict__ off) {
    if (threadIdx.x == 0) {
        int a = 0;
        for (int e = 0; e < NEXP; ++e) { off[e] = a; a += cnt[e]; }
        off[NEXP] = a;   // == TOKENS*TOPK
    }
}

// ---------------- GEMM1: h = silu(X@w1) * (X@w3), per expert (e==32 -> shared) ----------------
__global__ __launch_bounds__(256) void gemm1_kernel(
    const float* __restrict__ X,
    const float* __restrict__ w1, const float* __restrict__ w3,
    const float* __restrict__ sw1, const float* __restrict__ sw3,
    const int* __restrict__ cnt, const int* __restrict__ off,
    const int* __restrict__ tok_list,
    unsigned short* __restrict__ h_buf, unsigned short* __restrict__ h_sh)
{
    int e  = blockIdx.x >> 5;
    int mt = blockIdx.x & 31;
    int M = (e < NEXP) ? cnt[e] : TOKENS;
    int row0 = mt << 6;
    if (row0 >= M) return;
    int n0 = blockIdx.y << 6;

    const float* B1 = (e < NEXP) ? (w1 + (size_t)e * HID * INT_DIM) : sw1;
    const float* B3 = (e < NEXP) ? (w3 + (size_t)e * HID * INT_DIM) : sw3;

    __shared__ short As [64 * LDSP];
    __shared__ short Bs1[64 * LDSP];
    __shared__ short Bs3[64 * LDSP];

    int tid = threadIdx.x;
    // A staging: thread -> (row, 8-col chunk)
    int ar = tid >> 2;
    int ac = (tid & 3) * 8;
    int arr = row0 + ar;
    int tok;
    if (e < NEXP) {
        int rv = (arr < M) ? arr : (M - 1);
        tok = tok_list[e * TOKENS + rv];
    } else {
        tok = arr;
    }
    const float* xrow = X + (size_t)tok * HID + ac;
    short* as_dst = &As[ar * LDSP + ac];

    // B staging: thread -> (n, 8 consecutive k); coalesced across lanes at each j
    int bn  = tid & 63;
    int bkg = (tid >> 6) * 8;
    const float* b1p = B1 + (size_t)bkg * INT_DIM + n0 + bn;
    const float* b3p = B3 + (size_t)bkg * INT_DIM + n0 + bn;
    short* bs1_dst = &Bs1[bn * LDSP + bkg];
    short* bs3_dst = &Bs3[bn * LDSP + bkg];

    int lane = tid & 63;
    int wv = tid >> 6;
    int wm = (wv >> 1) * 32;
    int wn = (wv & 1) * 32;
    int fr = lane & 15;
    int kq = (lane >> 4) * 8;

    f32x4 accg[2][2] = {};
    f32x4 accu[2][2] = {};

    for (int k0 = 0; k0 < HID; k0 += BK) {
        float4 a0 = *(const float4*)(xrow + k0);
        float4 a1 = *(const float4*)(xrow + k0 + 4);
        BV8 av;
        av.u[0] = pk2bf(a0.x, a0.y);
        av.u[1] = pk2bf(a0.z, a0.w);
        av.u[2] = pk2bf(a1.x, a1.y);
        av.u[3] = pk2bf(a1.z, a1.w);
        *(bf16x8*)as_dst = av.v;

        const float* p1 = b1p + (size_t)k0 * INT_DIM;
        const float* p3 = b3p + (size_t)k0 * INT_DIM;
        float t1[8], t3[8];
        #pragma unroll
        for (int j2 = 0; j2 < 8; ++j2) {
            t1[j2] = p1[(size_t)j2 * INT_DIM];
            t3[j2] = p3[(size_t)j2 * INT_DIM];
        }
        BV8 bv1, bv3;
        #pragma unroll
        for (int j2 = 0; j2 < 4; ++j2) {
            bv1.u[j2] = pk2bf(t1[2*j2], t1[2*j2+1]);
            bv3.u[j2] = pk2bf(t3[2*j2], t3[2*j2+1]);
        }
        *(bf16x8*)bs1_dst = bv1.v;
        *(bf16x8*)bs3_dst = bv3.v;
        __syncthreads();

        bf16x8 af[2], b1f[2], b3f[2];
        #pragma unroll
        for (int i = 0; i < 2; ++i)
            af[i] = *(const bf16x8*)&As[(wm + i*16 + fr) * LDSP + kq];
        #pragma unroll
        for (int jj = 0; jj < 2; ++jj) {
            b1f[jj] = *(const bf16x8*)&Bs1[(wn + jj*16 + fr) * LDSP + kq];
            b3f[jj] = *(const bf16x8*)&Bs3[(wn + jj*16 + fr) * LDSP + kq];
        }
        #pragma unroll
        for (int i = 0; i < 2; ++i)
            #pragma unroll
            for (int jj = 0; jj < 2; ++jj) {
                accg[i][jj] = __builtin_amdgcn_mfma_f32_16x16x32_bf16(af[i], b1f[jj], accg[i][jj], 0, 0, 0);
                accu[i][jj] = __builtin_amdgcn_mfma_f32_16x16x32_bf16(af[i], b3f[jj], accu[i][jj], 0, 0, 0);
            }
        __syncthreads();
    }

    int hb = (e < NEXP) ? off[e] : 0;
    unsigned short* hptr = (e < NEXP) ? h_buf : h_sh;
    #pragma unroll
    for (int i = 0; i < 2; ++i) {
        #pragma unroll
        for (int p = 0; p < 4; ++p) {
            int row = wm + i*16 + (lane >> 4)*4 + p;   // C/D: row=(lane>>4)*4+reg, col=lane&15
            int gr = row0 + row;
            if (gr < M) {
                size_t rbase = (size_t)(hb + gr) * INT_DIM;
                #pragma unroll
                for (int jj = 0; jj < 2; ++jj) {
                    int col = n0 + wn + jj*16 + fr;
                    float gv = accg[i][jj][p];
                    float uv = accu[i][jj][p];
                    float hv = gv / (1.0f + __expf(-gv)) * uv;
                    hptr[rbase + col] = f2bf(hv);
                }
            }
        }
    }
}

// ---------------- GEMM2: out += wt * (h @ w2), per expert (e==32 -> shared, wt=1) ----------------
__global__ __launch_bounds__(256) void gemm2_kernel(
    const float* __restrict__ w2, const float* __restrict__ sw2,
    const int* __restrict__ cnt, const int* __restrict__ off,
    const int* __restrict__ tok_list, const float* __restrict__ wt_list,
    const unsigned short* __restrict__ h_buf, const unsigned short* __restrict__ h_sh,
    float* __restrict__ out)
{
    int e  = blockIdx.x >> 5;
    int mt = blockIdx.x & 31;
    int M = (e < NEXP) ? cnt[e] : TOKENS;
    int row0 = mt << 6;
    if (row0 >= M) return;
    int n0 = blockIdx.y << 6;

    const float* B2 = (e < NEXP) ? (w2 + (size_t)e * INT_DIM * HID) : sw2;
    int hb = (e < NEXP) ? off[e] : 0;
    const unsigned short* hsrc = (e < NEXP) ? h_buf : h_sh;

    __shared__ short As[64 * LDSP];
    __shared__ short Bs[64 * LDSP];

    int tid = threadIdx.x;
    int ar = tid >> 2;
    int ac = (tid & 3) * 8;
    int arr = row0 + ar;
    int rv = (arr < M) ? arr : (M - 1);
    const unsigned short* hrow = hsrc + (size_t)(hb + rv) * INT_DIM + ac;
    short* as_dst = &As[ar * LDSP + ac];

    int bn  = tid & 63;
    int bkg = (tid >> 6) * 8;
    const float* bp = B2 + (size_t)bkg * HID + n0 + bn;
    short* bs_dst = &Bs[bn * LDSP + bkg];

    int lane = tid & 63;
    int wv = tid >> 6;
    int wm = (wv >> 1) * 32;
    int wn = (wv & 1) * 32;
    int fr = lane & 15;
    int kq = (lane >> 4) * 8;

    f32x4 acc[2][2] = {};

    for (int k0 = 0; k0 < INT_DIM; k0 += BK) {
        *(bf16x8*)as_dst = *(const bf16x8*)(hrow + k0);   // h already bf16
        const float* p = bp + (size_t)k0 * HID;
        float tv[8];
        #pragma unroll
        for (int j2 = 0; j2 < 8; ++j2) tv[j2] = p[(size_t)j2 * HID];
        BV8 bv;
        #pragma unroll
        for (int j2 = 0; j2 < 4; ++j2) bv.u[j2] = pk2bf(tv[2*j2], tv[2*j2+1]);
        *(bf16x8*)bs_dst = bv.v;
        __syncthreads();

        bf16x8 af[2], bbf[2];
        #pragma unroll
        for (int i = 0; i < 2; ++i)
            af[i] = *(const bf16x8*)&As[(wm + i*16 + fr) * LDSP + kq];
        #pragma unroll
        for (int jj = 0; jj < 2; ++jj)
            bbf[jj] = *(const bf16x8*)&Bs[(wn + jj*16 + fr) * LDSP + kq];
        #pragma unroll
        for (int i = 0; i < 2; ++i)
            #pragma unroll
            for (int jj = 0; jj < 2; ++jj)
                acc[i][jj] = __builtin_amdgcn_mfma_f32_16x16x32_bf16(af[i], bbf[jj], acc[i][jj], 0, 0, 0);
        __syncthreads();
    }

    #pragma unroll
    for (int i = 0; i < 2; ++i) {
        #pragma unroll
        for (int p = 0; p < 4; ++p) {
            int row = wm + i*16 + (lane >> 4)*4 + p;
            int gr = row0 + row;
            if (gr < M) {
                int tok; float wt;
                if (e < NEXP) { tok = tok_list[e * TOKENS + gr]; wt = wt_list[e * TOKENS + gr]; }
                else          { tok = gr; wt = 1.0f; }
                float* orow = out + (size_t)tok * HID;
                #pragma unroll
                for (int jj = 0; jj < 2; ++jj) {
                    int col = n0 + wn + jj*16 + fr;
                    atomicAdd(&orow[col], acc[i][jj][p] * wt);
                }
            }
        }
    }
}

extern "C" void kernel_launch(void* const* d_in, const int* in_sizes, int n_in,
                              void* d_out, int out_size, void* d_ws, size_t ws_size,
                              hipStream_t stream) {
    const float* X   = (const float*)d_in[0];
    const float* GW  = (const float*)d_in[1];
    const float* GB  = (const float*)d_in[2];
    const float* w1  = (const float*)d_in[3];
    const float* w3  = (const float*)d_in[4];
    const float* w2  = (const float*)d_in[5];
    const float* sw1 = (const float*)d_in[6];
    const float* sw3 = (const float*)d_in[7];
    const float* sw2 = (const float*)d_in[8];
    float* out = (float*)d_out;

    char* ws = (char*)d_ws;
    int*   cnt      = (int*)ws;                       // 33 ints
    int*   off      = (int*)(ws + 256);               // 33 ints
    int*   tok_list = (int*)(ws + 512);               // 32*2048 ints
    float* wt_list  = (float*)(ws + 512 + NEXP*TOKENS*4);
    unsigned short* h_buf = (unsigned short*)(ws + (1 << 20));          // 16384 x 1408 bf16
    unsigned short* h_sh  = h_buf + (size_t)TOKENS * TOPK * INT_DIM;    // 2048 x 1408 bf16
    // total ws needed ~= 1MB + 52MB

    hipMemsetAsync(cnt, 0, 256, stream);
    hipMemsetAsync(d_out, 0, (size_t)TOKENS * HID * sizeof(float), stream);

    gate_kernel<<<TOKENS, 256, 0, stream>>>(X, GW, GB, cnt, tok_list, wt_list);
    prefix_kernel<<<1, 64, 0, stream>>>(cnt, off);
    gemm1_kernel<<<dim3(33 * 32, INT_DIM / 64), 256, 0, stream>>>(
        X, w1, w3, sw1, sw3, cnt, off, tok_list, h_buf, h_sh);
    gemm2_kernel<<<dim3(33 * 32, HID / 64), 256, 0, stream>>>(
        w2, sw2, cnt, off, tok_list, wt_list, h_buf, h_sh, out);
}